// Round 10
// baseline (1008.547 us; speedup 1.0000x reference)
//
#include <hip/hip_runtime.h>
#include <math.h>

#define N_NODES 100000
#define E_EDGES 1600000
#define D_IN    128
#define H_MID   32
#define C_OUT   5

#define NBKT   98     // coarse buckets: dst>>10, 99999>>10 = 97
#define BSHIFT 10
#define BNODES 1024   // nodes per bucket
#define BCAP   17500  // per-bucket staging capacity (mean 16327, +9 sigma)
#define SRC_BITS 17
#define SRC_MASK 0x1FFFF

#define KP 136        // k1 LDS k-stride in bf16 units

typedef __attribute__((ext_vector_type(8))) short bf16x8;
typedef __attribute__((ext_vector_type(4))) float f32x4;

// round-to-nearest-even fp32 -> bf16 bits
__device__ inline unsigned f2bf(float f) {
    unsigned u = __float_as_uint(f);
    return (u + 0x7FFFu + ((u >> 16) & 1u)) >> 16;
}

// ---------------- K1 (MFMA): [xrel|xroot] = x @ [Wrel|Wroot] ----------------
__global__ __launch_bounds__(256) void k1_mfma(
    const float* __restrict__ x,
    const float* __restrict__ Wrel,
    const float* __restrict__ Wroot,
    const float* __restrict__ b1,
    unsigned short* __restrict__ xrelh,
    float* __restrict__ xroot) {
    __shared__ unsigned short xs[64 * KP];
    __shared__ unsigned short wt[64 * KP];
    int tid = threadIdx.x;
    int nodeBase = blockIdx.x * 64;

    #pragma unroll
    for (int it = 0; it < 32; ++it) {
        int idx = it * 256 + tid;          // over [k=128][n=64]
        int k = idx >> 6, n = idx & 63;
        float wvv = (n < 32) ? Wrel[k * H_MID + n] : Wroot[k * H_MID + (n - 32)];
        wt[n * KP + k] = (unsigned short)f2bf(wvv);
    }
    #pragma unroll
    for (int it = 0; it < 16; ++it) {
        int idx = it * 256 + tid;          // row*64 + kpair
        int row = idx >> 6, kp = idx & 63;
        int node = nodeBase + row;
        float2 v = make_float2(0.f, 0.f);
        if (node < N_NODES)
            v = *(const float2*)(x + (size_t)node * D_IN + kp * 2);
        unsigned pk = f2bf(v.x) | (f2bf(v.y) << 16);
        *(unsigned*)(xs + row * KP + kp * 2) = pk;
    }
    __syncthreads();

    int lane = tid & 63;
    int wv = tid >> 6;
    int m = lane & 15;
    int quad = lane >> 4;

    f32x4 acc[4];
    #pragma unroll
    for (int nt = 0; nt < 4; ++nt) acc[nt] = (f32x4){0.f, 0.f, 0.f, 0.f};

    #pragma unroll
    for (int kk = 0; kk < 4; ++kk) {
        int k0 = kk * 32 + quad * 8;
        bf16x8 a = *(const bf16x8*)(xs + (wv * 16 + m) * KP + k0);
        #pragma unroll
        for (int nt = 0; nt < 4; ++nt) {
            bf16x8 b = *(const bf16x8*)(wt + (nt * 16 + m) * KP + k0);
            acc[nt] = __builtin_amdgcn_mfma_f32_16x16x32_bf16(a, b, acc[nt], 0, 0, 0);
        }
    }

    #pragma unroll
    for (int nt = 0; nt < 4; ++nt) {
        #pragma unroll
        for (int r = 0; r < 4; ++r) {
            int node = nodeBase + wv * 16 + quad * 4 + r;
            int colg = nt * 16 + m;
            if (node < N_NODES) {
                if (colg < H_MID) {
                    xrelh[(size_t)node * H_MID + colg] =
                        (unsigned short)f2bf(acc[nt][r]);
                } else {
                    int c = colg - H_MID;
                    xroot[(size_t)node * H_MID + c] = acc[nt][r] + b1[c];
                }
            }
        }
    }
}

// ---------------- tiny zero (bucket counters) ----------------
__global__ void k_zero_small(int* __restrict__ p, int n) {
    int i = threadIdx.x;
    if (i < n) p[i] = 0;
}

// -------- Pass A: counting-sort 1024 edges by coarse bucket in LDS --------
// staged element: int2 { (dstLow10 << 17) | src17 , w_bits }  (8 B/edge)
__global__ __launch_bounds__(1024) void k_binA(
    const int* __restrict__ src,
    const int* __restrict__ dst,
    const float* __restrict__ ew,
    int* __restrict__ bucket_cursor,
    int2* __restrict__ staged) {
    __shared__ int cnt[NBKT];
    __shared__ int lstart[NBKT];
    __shared__ int gbase[NBKT];
    __shared__ int scanbuf[128];
    __shared__ int2 ebuf[1024];
    __shared__ short bbuf[1024];
    int tid = threadIdx.x;
    int e = blockIdx.x * 1024 + tid;

    if (tid < NBKT) cnt[tid] = 0;
    __syncthreads();

    int b = 0, rank = 0, packed = 0, wbits = 0;
    bool valid = (e < E_EDGES);
    if (valid) {
        int d = dst[e];
        int s = src[e];
        wbits = __float_as_int(ew[e]);
        b = d >> BSHIFT;
        packed = ((d & (BNODES - 1)) << SRC_BITS) | s;
        rank = atomicAdd(&cnt[b], 1);
    }
    __syncthreads();

    if (tid < 128) scanbuf[tid] = (tid < NBKT) ? cnt[tid] : 0;
    __syncthreads();
    for (int off = 1; off < 128; off <<= 1) {
        int t = 0;
        if (tid < 128 && tid >= off) t = scanbuf[tid - off];
        __syncthreads();
        if (tid < 128) scanbuf[tid] += t;
        __syncthreads();
    }
    if (tid < NBKT) {
        lstart[tid] = scanbuf[tid] - cnt[tid];
        gbase[tid]  = atomicAdd(&bucket_cursor[tid], cnt[tid]);
    }
    __syncthreads();
    int total = scanbuf[NBKT - 1];

    if (valid) {
        int slot = lstart[b] + rank;
        ebuf[slot] = make_int2(packed, wbits);
        bbuf[slot] = (short)b;
    }
    __syncthreads();

    if (tid < total) {
        int2 ev = ebuf[tid];
        int bb = bbuf[tid];
        int gpos = gbase[bb] + (tid - lstart[bb]);
        if (gpos < BCAP)
            staged[(size_t)bb * BCAP + gpos] = ev;
    }
}

// -------- Agg1: per-bucket LDS accumulate + node update + projection -------
// 128KB LDS accumulator over the bucket's 1024-node window (rotated layout:
// col c of node n lives at n*32 + ((c+n)&31) -> all LDS ops conflict-free).
// Replaces csr scatter + layer-1 gather.
__global__ __launch_bounds__(1024) void k_agg1(
    const int* __restrict__ bucket_cursor,
    const int2* __restrict__ staged,
    const unsigned short* __restrict__ xrelh,
    const float* __restrict__ xroot,
    const float* __restrict__ Wrel2,
    const float* __restrict__ Wroot2,
    const float* __restrict__ b2,
    int* __restrict__ deg,
    float* __restrict__ h2rel,
    float* __restrict__ h2root) {
    __shared__ float agg[BNODES * H_MID];   // 128 KB
    __shared__ int hist[BNODES];            // 4 KB
    int tid = threadIdx.x;
    int b = blockIdx.x;
    int count = bucket_cursor[b];
    if (count > BCAP) count = BCAP;
    int nodeBase = b << BSHIFT;
    const int2* sp = staged + (size_t)b * BCAP;

    #pragma unroll
    for (int i = 0; i < H_MID; ++i) agg[i * BNODES + tid] = 0.f;
    hist[tid] = 0;
    __syncthreads();

    // edge phase: 32 lanes per edge (lane = column)
    int c = tid & 31;
    for (int i = (tid >> 5); i < count; i += 32) {
        int2 ev = sp[i];
        int local = ((unsigned)ev.x) >> SRC_BITS;
        int s = ev.x & SRC_MASK;
        float w = __int_as_float(ev.y);
        float v = __uint_as_float(((unsigned)xrelh[(size_t)s * H_MID + c]) << 16);
        atomicAdd(&agg[(local << 5) + ((c + local) & 31)], v * w);
        if (c == 0) atomicAdd(&hist[local], 1);
    }
    __syncthreads();

    // node phase: one thread per node
    int node = nodeBase + tid;
    if (node >= N_NODES) return;
    int dg = hist[tid];
    deg[node] = dg;
    float inv = 1.0f / fmaxf((float)dg, 1.0f);

    float4 xr[8];
    #pragma unroll
    for (int j = 0; j < 8; ++j)
        xr[j] = *(const float4*)(xroot + (size_t)node * H_MID + j * 4);

    float prel[C_OUT]  = {0.f, 0.f, 0.f, 0.f, 0.f};
    float proot[C_OUT] = {0.f, 0.f, 0.f, 0.f, 0.f};
    #pragma unroll
    for (int k = 0; k < H_MID; ++k) {
        float a = agg[(tid << 5) + ((k + tid) & 31)];   // bank (k+tid)%32: free
        float xv = ((const float*)&xr[k >> 2])[k & 3];
        float hv = fmaxf(a * inv + xv, 0.f);
        #pragma unroll
        for (int j = 0; j < C_OUT; ++j) {
            prel[j]  += hv * Wrel2[k * C_OUT + j];
            proot[j] += hv * Wroot2[k * C_OUT + j];
        }
    }
    #pragma unroll
    for (int j = 0; j < C_OUT; ++j) {
        h2rel[(size_t)node * C_OUT + j]  = prel[j];
        h2root[(size_t)node * C_OUT + j] = proot[j] + b2[j];
    }
}

// -------- Agg2: per-bucket LDS accumulate + mean + log_softmax -> out ------
__global__ __launch_bounds__(1024) void k_agg2(
    const int* __restrict__ bucket_cursor,
    const int2* __restrict__ staged,
    const float* __restrict__ h2rel,
    const float* __restrict__ h2root,
    const int* __restrict__ deg,
    float* __restrict__ out) {
    __shared__ float agg2[BNODES * C_OUT];  // 20 KB
    int tid = threadIdx.x;
    int b = blockIdx.x;
    int count = bucket_cursor[b];
    if (count > BCAP) count = BCAP;
    int nodeBase = b << BSHIFT;
    const int2* sp = staged + (size_t)b * BCAP;

    #pragma unroll
    for (int i = 0; i < C_OUT; ++i) agg2[i * BNODES + tid] = 0.f;
    __syncthreads();

    // edge phase: 8 lanes per edge, 5 active
    int c = tid & 7;
    for (int i = (tid >> 3); i < count; i += 128) {
        int2 ev = sp[i];
        if (c < C_OUT) {
            int local = ((unsigned)ev.x) >> SRC_BITS;
            int s = ev.x & SRC_MASK;
            atomicAdd(&agg2[local * C_OUT + c], h2rel[(size_t)s * C_OUT + c]);
        }
    }
    __syncthreads();

    int node = nodeBase + tid;
    if (node >= N_NODES) return;
    float inv = 1.0f / fmaxf((float)deg[node], 1.0f);
    float o[C_OUT];
    #pragma unroll
    for (int j = 0; j < C_OUT; ++j)
        o[j] = agg2[tid * C_OUT + j] * inv + h2root[(size_t)node * C_OUT + j];
    float m = o[0];
    #pragma unroll
    for (int j = 1; j < C_OUT; ++j) m = fmaxf(m, o[j]);
    float ssum = 0.f;
    #pragma unroll
    for (int j = 0; j < C_OUT; ++j) ssum += expf(o[j] - m);
    float lse = m + logf(ssum);
    #pragma unroll
    for (int j = 0; j < C_OUT; ++j)
        out[(size_t)node * C_OUT + j] = o[j] - lse;
}

extern "C" void kernel_launch(void* const* d_in, const int* in_sizes, int n_in,
                              void* d_out, int out_size, void* d_ws, size_t ws_size,
                              hipStream_t stream) {
    const float* x      = (const float*)d_in[0];
    const int*   ei     = (const int*)d_in[1];
    const float* ew     = (const float*)d_in[2];
    const float* Wrel1  = (const float*)d_in[3];
    const float* Wroot1 = (const float*)d_in[4];
    const float* b1     = (const float*)d_in[5];
    const float* Wrel2  = (const float*)d_in[6];
    const float* Wroot2 = (const float*)d_in[7];
    const float* b2     = (const float*)d_in[8];
    float* out = (float*)d_out;

    const int* src = ei;
    const int* dst = ei + E_EDGES;

    // Workspace (no aliasing: staged lives through k_agg2).
    // deg N | cursor 128 | staged 98*17500 int2 (13.7MB) | xrelh 32N ushort |
    // xroot 32N f | h2rel 5N | h2root 5N   -> ~36 MB total.
    char* ws = (char*)d_ws;
    int*   deg           = (int*)ws;                            // N
    int*   bucket_cursor = deg + N_NODES;                       // 128
    int2*  staged        = (int2*)(bucket_cursor + 128);        // NBKT*BCAP
    unsigned short* xrelh = (unsigned short*)(staged + (size_t)NBKT * BCAP);
    float* xroot         = (float*)(xrelh + (size_t)N_NODES * H_MID); // 32N
    float* h2rel         = xroot + (size_t)N_NODES * H_MID;     // 5N
    float* h2root        = h2rel + (size_t)N_NODES * C_OUT;     // 5N

    // --- stage edges into 1024-node buckets ---
    k_zero_small<<<1, 128, 0, stream>>>(bucket_cursor, 128);
    k_binA<<<(E_EDGES + 1023) / 1024, 1024, 0, stream>>>(src, dst, ew,
                                                         bucket_cursor, staged);

    // --- dense projections via MFMA ---
    k1_mfma<<<(N_NODES + 63) / 64, 256, 0, stream>>>(x, Wrel1, Wroot1, b1,
                                                     xrelh, xroot);

    // --- layer 1: LDS-window aggregate + node update + projections ---
    k_agg1<<<NBKT, 1024, 0, stream>>>(bucket_cursor, staged, xrelh, xroot,
                                      Wrel2, Wroot2, b2, deg, h2rel, h2root);

    // --- layer 2: LDS-window aggregate + mean + log_softmax ---
    k_agg2<<<NBKT, 1024, 0, stream>>>(bucket_cursor, staged, h2rel, h2root,
                                      deg, out);
}

// Round 11
// 244.825 us; speedup vs baseline: 4.1195x; 4.1195x over previous
//
#include <hip/hip_runtime.h>
#include <math.h>

#define N_NODES 100000
#define E_EDGES 1600000
#define D_IN    128
#define H_MID   32
#define C_OUT   5

#define NBKT   98     // coarse buckets: dst>>10, 99999>>10 = 97
#define BSHIFT 10
#define BNODES 1024   // nodes per bucket
#define BCAP   17500  // per-bucket staging capacity (mean 16384)
#define SRC_BITS 17
#define SRC_MASK 0x1FFFF

#define KP 136        // LDS k-stride in bf16 units

typedef __attribute__((ext_vector_type(8))) short bf16x8;
typedef __attribute__((ext_vector_type(4))) float f32x4;

// round-to-nearest-even fp32 -> bf16 bits
__device__ inline unsigned f2bf(float f) {
    unsigned u = __float_as_uint(f);
    return (u + 0x7FFFu + ((u >> 16) & 1u)) >> 16;
}

// ---------------- K1 (MFMA): [xrel|xroot] = x @ [Wrel|Wroot] ----------------
__global__ __launch_bounds__(256) void k1_mfma(
    const float* __restrict__ x,
    const float* __restrict__ Wrel,
    const float* __restrict__ Wroot,
    const float* __restrict__ b1,
    unsigned short* __restrict__ xrelh,
    float* __restrict__ xroot) {
    __shared__ unsigned short xs[64 * KP];
    __shared__ unsigned short wt[64 * KP];
    int tid = threadIdx.x;
    int nodeBase = blockIdx.x * 64;

    #pragma unroll
    for (int it = 0; it < 32; ++it) {
        int idx = it * 256 + tid;          // over [k=128][n=64]
        int k = idx >> 6, n = idx & 63;
        float wvv = (n < 32) ? Wrel[k * H_MID + n] : Wroot[k * H_MID + (n - 32)];
        wt[n * KP + k] = (unsigned short)f2bf(wvv);
    }
    #pragma unroll
    for (int it = 0; it < 16; ++it) {
        int idx = it * 256 + tid;          // row*64 + kpair
        int row = idx >> 6, kp = idx & 63;
        int node = nodeBase + row;
        float2 v = make_float2(0.f, 0.f);
        if (node < N_NODES)
            v = *(const float2*)(x + (size_t)node * D_IN + kp * 2);
        unsigned pk = f2bf(v.x) | (f2bf(v.y) << 16);
        *(unsigned*)(xs + row * KP + kp * 2) = pk;
    }
    __syncthreads();

    int lane = tid & 63;
    int wv = tid >> 6;
    int m = lane & 15;
    int quad = lane >> 4;

    f32x4 acc[4];
    #pragma unroll
    for (int nt = 0; nt < 4; ++nt) acc[nt] = (f32x4){0.f, 0.f, 0.f, 0.f};

    #pragma unroll
    for (int kk = 0; kk < 4; ++kk) {
        int k0 = kk * 32 + quad * 8;
        bf16x8 a = *(const bf16x8*)(xs + (wv * 16 + m) * KP + k0);
        #pragma unroll
        for (int nt = 0; nt < 4; ++nt) {
            bf16x8 b = *(const bf16x8*)(wt + (nt * 16 + m) * KP + k0);
            acc[nt] = __builtin_amdgcn_mfma_f32_16x16x32_bf16(a, b, acc[nt], 0, 0, 0);
        }
    }

    #pragma unroll
    for (int nt = 0; nt < 4; ++nt) {
        #pragma unroll
        for (int r = 0; r < 4; ++r) {
            int node = nodeBase + wv * 16 + quad * 4 + r;
            int colg = nt * 16 + m;
            if (node < N_NODES) {
                if (colg < H_MID) {
                    xrelh[(size_t)node * H_MID + colg] =
                        (unsigned short)f2bf(acc[nt][r]);
                } else {
                    int c = colg - H_MID;
                    xroot[(size_t)node * H_MID + c] = acc[nt][r] + b1[c];
                }
            }
        }
    }
}

// ---------------- tiny zero (bucket counters) ----------------
__global__ void k_zero_small(int* __restrict__ p, int n) {
    int i = threadIdx.x;
    if (i < n) p[i] = 0;
}

// -------- Pass A: counting-sort 1024 edges by coarse bucket in LDS --------
// staged element: int2 { (dstLow10 << 17) | src17 , w_bits }  (8 B/edge)
__global__ __launch_bounds__(1024) void k_binA(
    const int* __restrict__ src,
    const int* __restrict__ dst,
    const float* __restrict__ ew,
    int* __restrict__ bucket_cursor,
    int2* __restrict__ staged) {
    __shared__ int cnt[NBKT];
    __shared__ int lstart[NBKT];
    __shared__ int gbase[NBKT];
    __shared__ int scanbuf[128];
    __shared__ int2 ebuf[1024];
    __shared__ short bbuf[1024];
    int tid = threadIdx.x;
    int e = blockIdx.x * 1024 + tid;

    if (tid < NBKT) cnt[tid] = 0;
    __syncthreads();

    int b = 0, rank = 0, packed = 0, wbits = 0;
    bool valid = (e < E_EDGES);
    if (valid) {
        int d = dst[e];
        int s = src[e];
        wbits = __float_as_int(ew[e]);
        b = d >> BSHIFT;
        packed = ((d & (BNODES - 1)) << SRC_BITS) | s;
        rank = atomicAdd(&cnt[b], 1);
    }
    __syncthreads();

    if (tid < 128) scanbuf[tid] = (tid < NBKT) ? cnt[tid] : 0;
    __syncthreads();
    for (int off = 1; off < 128; off <<= 1) {
        int t = 0;
        if (tid < 128 && tid >= off) t = scanbuf[tid - off];
        __syncthreads();
        if (tid < 128) scanbuf[tid] += t;
        __syncthreads();
    }
    if (tid < NBKT) {
        lstart[tid] = scanbuf[tid] - cnt[tid];
        gbase[tid]  = atomicAdd(&bucket_cursor[tid], cnt[tid]);
    }
    __syncthreads();
    int total = scanbuf[NBKT - 1];

    if (valid) {
        int slot = lstart[b] + rank;
        ebuf[slot] = make_int2(packed, wbits);
        bbuf[slot] = (short)b;
    }
    __syncthreads();

    if (tid < total) {
        int2 ev = ebuf[tid];
        int bb = bbuf[tid];
        int gpos = gbase[bb] + (tid - lstart[bb]);
        if (gpos < BCAP)
            staged[(size_t)bb * BCAP + gpos] = ev;
    }
}

// -------- exclusive scan of the 98 bucket counts -> bucket_base ----------
__global__ void k_bktscan(const int* __restrict__ bucket_cursor,
                          int* __restrict__ bucket_base) {
    __shared__ int s[128];
    int i = threadIdx.x;
    int c = (i < NBKT) ? bucket_cursor[i] : 0;
    int v = (c > BCAP) ? BCAP : c;
    s[i] = v;
    __syncthreads();
    for (int off = 1; off < 128; off <<= 1) {
        int t = (i >= off) ? s[i - off] : 0;
        __syncthreads();
        s[i] += t;
        __syncthreads();
    }
    if (i < NBKT) bucket_base[i] = s[i] - v;
}

// -------- Pass B: per-bucket LDS histogram + scan + L2-local scatter -------
__global__ __launch_bounds__(1024) void k_binB2(
    const int* __restrict__ bucket_cursor,
    const int* __restrict__ bucket_base,
    const int2* __restrict__ staged,
    int* __restrict__ deg,
    int* __restrict__ offsets,
    int2* __restrict__ csr8) {
    __shared__ int hist[BNODES];
    __shared__ int scanb[BNODES];
    __shared__ int cur[BNODES];
    int tid = threadIdx.x;
    int b = blockIdx.x;
    int count = bucket_cursor[b];
    if (count > BCAP) count = BCAP;
    int base = bucket_base[b];
    int nodeBase = b << BSHIFT;
    const int2* sp = staged + (size_t)b * BCAP;

    hist[tid] = 0;
    __syncthreads();

    for (int i = tid; i < count; i += 1024)
        atomicAdd(&hist[((unsigned)sp[i].x) >> SRC_BITS], 1);
    __syncthreads();

    int v = hist[tid];
    scanb[tid] = v;
    __syncthreads();
    for (int off = 1; off < BNODES; off <<= 1) {
        int t = (tid >= off) ? scanb[tid - off] : 0;
        __syncthreads();
        scanb[tid] += t;
        __syncthreads();
    }
    int excl = scanb[tid] - v;
    int node = nodeBase + tid;
    if (node < N_NODES) {
        deg[node]     = v;
        offsets[node] = base + excl;
    }
    cur[tid] = excl;
    __syncthreads();

    for (int i = tid; i < count; i += 1024) {
        int2 ev = sp[i];
        int local = ((unsigned)ev.x) >> SRC_BITS;
        int pos = atomicAdd(&cur[local], 1);
        csr8[base + pos] = make_int2(ev.x & SRC_MASK, ev.y);
    }
}

// -------- Layer 1 fused: bf16 gather-mean + root + relu + project ----------
// 16 nodes/block, 16 lanes/node, 2 columns per lane; 8 loads in flight.
__global__ __launch_bounds__(256) void k_layer1(
    const int* __restrict__ offsets,
    const int* __restrict__ deg,
    const int2* __restrict__ csr8,
    const unsigned short* __restrict__ xrelh,
    const float* __restrict__ xroot,
    const float* __restrict__ Wrel2,
    const float* __restrict__ Wroot2,
    const float* __restrict__ b2,
    float* __restrict__ h2rel,
    float* __restrict__ h2root) {
    int node = blockIdx.x * 16 + (threadIdx.x >> 4);
    int lane = threadIdx.x & 15;           // 2 cols: 2*lane, 2*lane+1
    int beg = offsets[node];
    int dg  = deg[node];
    int end = beg + dg;

    float acc0 = 0.f, acc1 = 0.f;
    int i = beg;
    for (; i + 8 <= end; i += 8) {
        int2 e[8];
        unsigned v[8];
        #pragma unroll
        for (int u = 0; u < 8; ++u) e[u] = csr8[i + u];
        #pragma unroll
        for (int u = 0; u < 8; ++u)
            v[u] = *(const unsigned*)(xrelh + (size_t)e[u].x * H_MID + lane * 2);
        #pragma unroll
        for (int u = 0; u < 8; ++u) {
            float w = __int_as_float(e[u].y);
            acc0 += __uint_as_float((v[u] & 0xFFFFu) << 16) * w;
            acc1 += __uint_as_float(v[u] & 0xFFFF0000u) * w;
        }
    }
    for (; i < end; ++i) {
        int2 e0 = csr8[i];
        unsigned v0 = *(const unsigned*)(xrelh + (size_t)e0.x * H_MID + lane * 2);
        float w0 = __int_as_float(e0.y);
        acc0 += __uint_as_float((v0 & 0xFFFFu) << 16) * w0;
        acc1 += __uint_as_float(v0 & 0xFFFF0000u) * w0;
    }

    float inv = 1.0f / fmaxf((float)dg, 1.0f);
    float2 rt = *(const float2*)(xroot + (size_t)node * H_MID + lane * 2);
    float h0 = fmaxf(acc0 * inv + rt.x, 0.f);
    float h1 = fmaxf(acc1 * inv + rt.y, 0.f);

    float p[2 * C_OUT];
    #pragma unroll
    for (int j = 0; j < C_OUT; ++j) {
        p[j]         = h0 * Wrel2[(2 * lane) * C_OUT + j]
                     + h1 * Wrel2[(2 * lane + 1) * C_OUT + j];
        p[C_OUT + j] = h0 * Wroot2[(2 * lane) * C_OUT + j]
                     + h1 * Wroot2[(2 * lane + 1) * C_OUT + j];
    }
    #pragma unroll
    for (int mm = 8; mm > 0; mm >>= 1) {
        #pragma unroll
        for (int j = 0; j < 2 * C_OUT; ++j)
            p[j] += __shfl_xor(p[j], mm, 16);
    }
    if (lane == 0) {
        #pragma unroll
        for (int j = 0; j < C_OUT; ++j) {
            h2rel[(size_t)node * C_OUT + j]  = p[j];
            h2root[(size_t)node * C_OUT + j] = p[C_OUT + j] + b2[j];
        }
    }
}

// -------- Layer 2 + log_softmax fused: 32 nodes/block, 8 lanes/node --------
__global__ __launch_bounds__(256) void k_layer2(
    const int* __restrict__ offsets,
    const int* __restrict__ deg,
    const int2* __restrict__ csr8,
    const float* __restrict__ h2rel,
    const float* __restrict__ h2root,
    float* __restrict__ out) {
    int node = blockIdx.x * 32 + (threadIdx.x >> 3);
    int lane = threadIdx.x & 7;
    int beg = offsets[node];
    int dg  = deg[node];
    int end = beg + dg;

    float acc = 0.f;
    if (lane < C_OUT) {
        int i = beg;
        for (; i + 8 <= end; i += 8) {
            int s[8];
            float v[8];
            #pragma unroll
            for (int u = 0; u < 8; ++u) s[u] = csr8[i + u].x;
            #pragma unroll
            for (int u = 0; u < 8; ++u)
                v[u] = h2rel[(size_t)s[u] * C_OUT + lane];
            #pragma unroll
            for (int u = 0; u < 8; ++u) acc += v[u];
        }
        for (; i < end; ++i)
            acc += h2rel[(size_t)csr8[i].x * C_OUT + lane];
    }
    float inv = 1.0f / fmaxf((float)dg, 1.0f);
    float o = (lane < C_OUT)
                  ? acc * inv + h2root[(size_t)node * C_OUT + lane]
                  : -INFINITY;
    float m = o;
    #pragma unroll
    for (int dd = 4; dd > 0; dd >>= 1) m = fmaxf(m, __shfl_xor(m, dd, 8));
    float e = (lane < C_OUT) ? expf(o - m) : 0.f;
    float ssum = e;
    #pragma unroll
    for (int dd = 4; dd > 0; dd >>= 1) ssum += __shfl_xor(ssum, dd, 8);
    float lse = m + logf(ssum);
    if (lane < C_OUT)
        out[(size_t)node * C_OUT + lane] = o - lse;
}

extern "C" void kernel_launch(void* const* d_in, const int* in_sizes, int n_in,
                              void* d_out, int out_size, void* d_ws, size_t ws_size,
                              hipStream_t stream) {
    const float* x      = (const float*)d_in[0];
    const int*   ei     = (const int*)d_in[1];
    const float* ew     = (const float*)d_in[2];
    const float* Wrel1  = (const float*)d_in[3];
    const float* Wroot1 = (const float*)d_in[4];
    const float* b1     = (const float*)d_in[5];
    const float* Wrel2  = (const float*)d_in[6];
    const float* Wroot2 = (const float*)d_in[7];
    const float* b2     = (const float*)d_in[8];
    float* out = (float*)d_out;

    const int* src = ei;
    const int* dst = ei + E_EDGES;

    // Workspace (4B units). staged (98*17500 int2 = 13.7MB) aliases
    // xrelh+xroot (6.4+12.8=19.2MB) — dead before k1_mfma writes there.
    char* ws = (char*)d_ws;
    int*   deg           = (int*)ws;                            // N
    int*   bucket_cursor = deg + N_NODES;                       // 128
    int*   bucket_base   = bucket_cursor + 128;                 // 128
    int*   offsets       = bucket_base + 128;                   // N
    int2*  csr8          = (int2*)(offsets + N_NODES);          // E int2
    unsigned short* xrelh = (unsigned short*)(csr8 + E_EDGES);  // 32N ushort
    float* xroot         = (float*)(xrelh + (size_t)N_NODES * H_MID); // 32N
    float* h2rel         = xroot + (size_t)N_NODES * H_MID;     // 5N
    float* h2root        = h2rel + (size_t)N_NODES * C_OUT;     // 5N
    int2*  staged        = (int2*)xrelh;                        // alias

    // --- binned CSR build ---
    k_zero_small<<<1, 128, 0, stream>>>(bucket_cursor, 128);
    k_binA<<<(E_EDGES + 1023) / 1024, 1024, 0, stream>>>(src, dst, ew,
                                                         bucket_cursor, staged);
    k_bktscan<<<1, 128, 0, stream>>>(bucket_cursor, bucket_base);
    k_binB2<<<NBKT, 1024, 0, stream>>>(bucket_cursor, bucket_base, staged,
                                       deg, offsets, csr8);

    // --- dense projections via MFMA (after staging is dead) ---
    k1_mfma<<<(N_NODES + 63) / 64, 256, 0, stream>>>(x, Wrel1, Wroot1, b1,
                                                     xrelh, xroot);

    // --- layer 1 fused gather + node update + layer-2 projections ---
    k_layer1<<<N_NODES / 16, 256, 0, stream>>>(offsets, deg, csr8,
                                               xrelh, xroot, Wrel2, Wroot2, b2,
                                               h2rel, h2root);

    // --- layer 2 gather + log_softmax (fused) ---
    k_layer2<<<N_NODES / 32, 256, 0, stream>>>(offsets, deg, csr8,
                                               h2rel, h2root, out);
}

// Round 12
// 231.225 us; speedup vs baseline: 4.3618x; 1.0588x over previous
//
#include <hip/hip_runtime.h>
#include <math.h>

#define N_NODES 100000
#define E_EDGES 1600000
#define D_IN    128
#define H_MID   32
#define C_OUT   5

#define NBKT   98     // coarse buckets: dst>>10, 99999>>10 = 97
#define BSHIFT 10
#define BNODES 1024   // nodes per bucket
#define BCAP   17500  // per-bucket staging capacity (mean 16384)
#define SRC_BITS 17
#define SRC_MASK 0x1FFFF

#define KP 136        // LDS k-stride in bf16 units (x-tile)

typedef __attribute__((ext_vector_type(8))) short bf16x8;
typedef __attribute__((ext_vector_type(4))) float f32x4;

// round-to-nearest-even fp32 -> bf16 bits
__device__ inline unsigned f2bf(float f) {
    unsigned u = __float_as_uint(f);
    return (u + 0x7FFFu + ((u >> 16) & 1u)) >> 16;
}

// ---------------- prep: zero cursors + build transposed bf16 W1 panel ------
__global__ void k_prep(const float* __restrict__ Wrel,
                       const float* __restrict__ Wroot,
                       int* __restrict__ bucket_cursor,
                       unsigned short* __restrict__ wt_g) {
    int tid = threadIdx.x;                 // 256
    if (tid < 128) bucket_cursor[tid] = 0;
    for (int i = tid; i < 64 * 128; i += 256) {
        int n = i >> 7, k = i & 127;
        float v = (n < H_MID) ? Wrel[k * H_MID + n] : Wroot[k * H_MID + (n - H_MID)];
        wt_g[i] = (unsigned short)f2bf(v);   // wt_g[n][k]
    }
}

// ---------------- K1 (MFMA): [xrel|xroot] = x @ [Wrel|Wroot] ----------------
// 256 threads = 4 waves; M=64 nodes, N=64, K=128. x tile in LDS (bf16);
// B-fragments read directly from the 16KB L1-resident wt_g table.
__global__ __launch_bounds__(256) void k1_mfma(
    const float* __restrict__ x,
    const unsigned short* __restrict__ wt_g,
    const float* __restrict__ b1,
    unsigned short* __restrict__ xrelh,
    float* __restrict__ xroot) {
    __shared__ unsigned short xs[64 * KP];
    int tid = threadIdx.x;
    int nodeBase = blockIdx.x * 64;

    #pragma unroll
    for (int it = 0; it < 16; ++it) {
        int idx = it * 256 + tid;          // row*64 + kpair
        int row = idx >> 6, kp = idx & 63;
        int node = nodeBase + row;
        float2 v = make_float2(0.f, 0.f);
        if (node < N_NODES)
            v = *(const float2*)(x + (size_t)node * D_IN + kp * 2);
        unsigned pk = f2bf(v.x) | (f2bf(v.y) << 16);
        *(unsigned*)(xs + row * KP + kp * 2) = pk;
    }
    __syncthreads();

    int lane = tid & 63;
    int wv = tid >> 6;
    int m = lane & 15;
    int quad = lane >> 4;

    f32x4 acc[4];
    #pragma unroll
    for (int nt = 0; nt < 4; ++nt) acc[nt] = (f32x4){0.f, 0.f, 0.f, 0.f};

    #pragma unroll
    for (int kk = 0; kk < 4; ++kk) {
        int k0 = kk * 32 + quad * 8;
        bf16x8 a = *(const bf16x8*)(xs + (wv * 16 + m) * KP + k0);
        #pragma unroll
        for (int nt = 0; nt < 4; ++nt) {
            bf16x8 b = *(const bf16x8*)(wt_g + (nt * 16 + m) * 128 + k0);
            acc[nt] = __builtin_amdgcn_mfma_f32_16x16x32_bf16(a, b, acc[nt], 0, 0, 0);
        }
    }

    #pragma unroll
    for (int nt = 0; nt < 4; ++nt) {
        #pragma unroll
        for (int r = 0; r < 4; ++r) {
            int node = nodeBase + wv * 16 + quad * 4 + r;
            int colg = nt * 16 + m;
            if (node < N_NODES) {
                if (colg < H_MID) {
                    xrelh[(size_t)node * H_MID + colg] =
                        (unsigned short)f2bf(acc[nt][r]);
                } else {
                    int c = colg - H_MID;
                    xroot[(size_t)node * H_MID + c] = acc[nt][r] + b1[c];
                }
            }
        }
    }
}

// -------- Pass A: counting-sort 2048 edges by coarse bucket in LDS --------
// staged element: int2 { (dstLow10 << 17) | src17 , w_bits }  (8 B/edge)
__global__ __launch_bounds__(1024) void k_binA(
    const int* __restrict__ src,
    const int* __restrict__ dst,
    const float* __restrict__ ew,
    int* __restrict__ bucket_cursor,
    int2* __restrict__ staged) {
    __shared__ int cnt[NBKT];
    __shared__ int lstart[NBKT];
    __shared__ int gbase[NBKT];
    __shared__ int scanbuf[128];
    __shared__ int2 ebuf[2048];
    __shared__ short bbuf[2048];
    int tid = threadIdx.x;
    int eBase = blockIdx.x * 2048;

    if (tid < NBKT) cnt[tid] = 0;
    __syncthreads();

    int b[2], rank[2], packed[2], wbits[2];
    bool valid[2];
    #pragma unroll
    for (int u = 0; u < 2; ++u) {
        int e = eBase + u * 1024 + tid;
        valid[u] = (e < E_EDGES);
        b[u] = 0; rank[u] = 0; packed[u] = 0; wbits[u] = 0;
        if (valid[u]) {
            int d = dst[e];
            int s = src[e];
            wbits[u] = __float_as_int(ew[e]);
            b[u] = d >> BSHIFT;
            packed[u] = ((d & (BNODES - 1)) << SRC_BITS) | s;
            rank[u] = atomicAdd(&cnt[b[u]], 1);
        }
    }
    __syncthreads();

    if (tid < 128) scanbuf[tid] = (tid < NBKT) ? cnt[tid] : 0;
    __syncthreads();
    for (int off = 1; off < 128; off <<= 1) {
        int t = 0;
        if (tid < 128 && tid >= off) t = scanbuf[tid - off];
        __syncthreads();
        if (tid < 128) scanbuf[tid] += t;
        __syncthreads();
    }
    if (tid < NBKT) {
        lstart[tid] = scanbuf[tid] - cnt[tid];
        gbase[tid]  = atomicAdd(&bucket_cursor[tid], cnt[tid]);
    }
    __syncthreads();
    int total = scanbuf[NBKT - 1];

    #pragma unroll
    for (int u = 0; u < 2; ++u) {
        if (valid[u]) {
            int slot = lstart[b[u]] + rank[u];
            ebuf[slot] = make_int2(packed[u], wbits[u]);
            bbuf[slot] = (short)b[u];
        }
    }
    __syncthreads();

    for (int t = tid; t < total; t += 1024) {
        int2 ev = ebuf[t];
        int bb = bbuf[t];
        int gpos = gbase[bb] + (t - lstart[bb]);
        if (gpos < BCAP)
            staged[(size_t)bb * BCAP + gpos] = ev;
    }
}

// -------- Pass B: in-block base scan + per-bucket LDS hist + scatter -------
__global__ __launch_bounds__(1024) void k_binB2(
    const int* __restrict__ bucket_cursor,
    const int2* __restrict__ staged,
    int* __restrict__ deg,
    int* __restrict__ offsets,
    int2* __restrict__ csr8) {
    __shared__ int hist[BNODES];
    __shared__ int scanb[BNODES];
    __shared__ int cur[BNODES];
    __shared__ int sbase[128];
    int tid = threadIdx.x;
    int b = blockIdx.x;

    // in-block exclusive scan of clamped bucket counts -> base for bucket b
    if (tid < 128) {
        int c = (tid < NBKT) ? bucket_cursor[tid] : 0;
        sbase[tid] = (c > BCAP) ? BCAP : c;
    }
    hist[tid] = 0;
    __syncthreads();
    for (int off = 1; off < 128; off <<= 1) {
        int t = 0;
        if (tid < 128 && tid >= off) t = sbase[tid - off];
        __syncthreads();
        if (tid < 128) sbase[tid] += t;
        __syncthreads();
    }
    int count = bucket_cursor[b];
    if (count > BCAP) count = BCAP;
    int base = sbase[b] - count;           // exclusive
    int nodeBase = b << BSHIFT;
    const int2* sp = staged + (size_t)b * BCAP;

    for (int i = tid; i < count; i += 1024)
        atomicAdd(&hist[((unsigned)sp[i].x) >> SRC_BITS], 1);
    __syncthreads();

    int v = hist[tid];
    scanb[tid] = v;
    __syncthreads();
    for (int off = 1; off < BNODES; off <<= 1) {
        int t = (tid >= off) ? scanb[tid - off] : 0;
        __syncthreads();
        scanb[tid] += t;
        __syncthreads();
    }
    int excl = scanb[tid] - v;
    int node = nodeBase + tid;
    if (node < N_NODES) {
        deg[node]     = v;
        offsets[node] = base + excl;
    }
    cur[tid] = excl;
    __syncthreads();

    for (int i = tid; i < count; i += 1024) {
        int2 ev = sp[i];
        int local = ((unsigned)ev.x) >> SRC_BITS;
        int pos = atomicAdd(&cur[local], 1);
        csr8[base + pos] = make_int2(ev.x & SRC_MASK, ev.y);
    }
}

// -------- Layer 1 fused: bf16 gather-mean + root + relu + project ----------
__global__ __launch_bounds__(256) void k_layer1(
    const int* __restrict__ offsets,
    const int* __restrict__ deg,
    const int2* __restrict__ csr8,
    const unsigned short* __restrict__ xrelh,
    const float* __restrict__ xroot,
    const float* __restrict__ Wrel2,
    const float* __restrict__ Wroot2,
    const float* __restrict__ b2,
    float* __restrict__ h2rel,
    float* __restrict__ h2root) {
    int node = blockIdx.x * 16 + (threadIdx.x >> 4);
    int lane = threadIdx.x & 15;           // 2 cols: 2*lane, 2*lane+1
    int beg = offsets[node];
    int dg  = deg[node];
    int end = beg + dg;

    float acc0 = 0.f, acc1 = 0.f;
    int i = beg;
    for (; i + 8 <= end; i += 8) {
        int2 e[8];
        unsigned v[8];
        #pragma unroll
        for (int u = 0; u < 8; ++u) e[u] = csr8[i + u];
        #pragma unroll
        for (int u = 0; u < 8; ++u)
            v[u] = *(const unsigned*)(xrelh + (size_t)e[u].x * H_MID + lane * 2);
        #pragma unroll
        for (int u = 0; u < 8; ++u) {
            float w = __int_as_float(e[u].y);
            acc0 += __uint_as_float((v[u] & 0xFFFFu) << 16) * w;
            acc1 += __uint_as_float(v[u] & 0xFFFF0000u) * w;
        }
    }
    for (; i < end; ++i) {
        int2 e0 = csr8[i];
        unsigned v0 = *(const unsigned*)(xrelh + (size_t)e0.x * H_MID + lane * 2);
        float w0 = __int_as_float(e0.y);
        acc0 += __uint_as_float((v0 & 0xFFFFu) << 16) * w0;
        acc1 += __uint_as_float(v0 & 0xFFFF0000u) * w0;
    }

    float inv = 1.0f / fmaxf((float)dg, 1.0f);
    float2 rt = *(const float2*)(xroot + (size_t)node * H_MID + lane * 2);
    float h0 = fmaxf(acc0 * inv + rt.x, 0.f);
    float h1 = fmaxf(acc1 * inv + rt.y, 0.f);

    float p[2 * C_OUT];
    #pragma unroll
    for (int j = 0; j < C_OUT; ++j) {
        p[j]         = h0 * Wrel2[(2 * lane) * C_OUT + j]
                     + h1 * Wrel2[(2 * lane + 1) * C_OUT + j];
        p[C_OUT + j] = h0 * Wroot2[(2 * lane) * C_OUT + j]
                     + h1 * Wroot2[(2 * lane + 1) * C_OUT + j];
    }
    #pragma unroll
    for (int mm = 8; mm > 0; mm >>= 1) {
        #pragma unroll
        for (int j = 0; j < 2 * C_OUT; ++j)
            p[j] += __shfl_xor(p[j], mm, 16);
    }
    if (lane == 0) {
        #pragma unroll
        for (int j = 0; j < C_OUT; ++j) {
            h2rel[(size_t)node * C_OUT + j]  = p[j];
            h2root[(size_t)node * C_OUT + j] = p[C_OUT + j] + b2[j];
        }
    }
}

// -------- Layer 2 + log_softmax fused: 32 nodes/block, 8 lanes/node --------
__global__ __launch_bounds__(256) void k_layer2(
    const int* __restrict__ offsets,
    const int* __restrict__ deg,
    const int2* __restrict__ csr8,
    const float* __restrict__ h2rel,
    const float* __restrict__ h2root,
    float* __restrict__ out) {
    int node = blockIdx.x * 32 + (threadIdx.x >> 3);
    int lane = threadIdx.x & 7;
    int beg = offsets[node];
    int dg  = deg[node];
    int end = beg + dg;

    float acc = 0.f;
    if (lane < C_OUT) {
        int i = beg;
        for (; i + 8 <= end; i += 8) {
            int s[8];
            float v[8];
            #pragma unroll
            for (int u = 0; u < 8; ++u) s[u] = csr8[i + u].x;
            #pragma unroll
            for (int u = 0; u < 8; ++u)
                v[u] = h2rel[(size_t)s[u] * C_OUT + lane];
            #pragma unroll
            for (int u = 0; u < 8; ++u) acc += v[u];
        }
        for (; i < end; ++i)
            acc += h2rel[(size_t)csr8[i].x * C_OUT + lane];
    }
    float inv = 1.0f / fmaxf((float)dg, 1.0f);
    float o = (lane < C_OUT)
                  ? acc * inv + h2root[(size_t)node * C_OUT + lane]
                  : -INFINITY;
    float m = o;
    #pragma unroll
    for (int dd = 4; dd > 0; dd >>= 1) m = fmaxf(m, __shfl_xor(m, dd, 8));
    float e = (lane < C_OUT) ? expf(o - m) : 0.f;
    float ssum = e;
    #pragma unroll
    for (int dd = 4; dd > 0; dd >>= 1) ssum += __shfl_xor(ssum, dd, 8);
    float lse = m + logf(ssum);
    if (lane < C_OUT)
        out[(size_t)node * C_OUT + lane] = o - lse;
}

extern "C" void kernel_launch(void* const* d_in, const int* in_sizes, int n_in,
                              void* d_out, int out_size, void* d_ws, size_t ws_size,
                              hipStream_t stream) {
    const float* x      = (const float*)d_in[0];
    const int*   ei     = (const int*)d_in[1];
    const float* ew     = (const float*)d_in[2];
    const float* Wrel1  = (const float*)d_in[3];
    const float* Wroot1 = (const float*)d_in[4];
    const float* b1     = (const float*)d_in[5];
    const float* Wrel2  = (const float*)d_in[6];
    const float* Wroot2 = (const float*)d_in[7];
    const float* b2     = (const float*)d_in[8];
    float* out = (float*)d_out;

    const int* src = ei;
    const int* dst = ei + E_EDGES;

    // Workspace (4B units). staged (98*17500 int2 = 13.7MB) aliases
    // xrelh+xroot (6.4+12.8=19.2MB) — dead before k1_mfma writes there.
    char* ws = (char*)d_ws;
    int*   deg           = (int*)ws;                            // N
    int*   bucket_cursor = deg + N_NODES;                       // 128
    unsigned short* wt_g = (unsigned short*)(bucket_cursor + 128); // 64*128 bf16
    int*   offsets       = (int*)(wt_g + 64 * 128);             // N
    int2*  csr8          = (int2*)(offsets + N_NODES);          // E int2
    unsigned short* xrelh = (unsigned short*)(csr8 + E_EDGES);  // 32N ushort
    float* xroot         = (float*)(xrelh + (size_t)N_NODES * H_MID); // 32N
    float* h2rel         = xroot + (size_t)N_NODES * H_MID;     // 5N
    float* h2root        = h2rel + (size_t)N_NODES * C_OUT;     // 5N
    int2*  staged        = (int2*)xrelh;                        // alias

    // --- prep: zero cursors + bf16 W panel ---
    k_prep<<<1, 256, 0, stream>>>(Wrel1, Wroot1, bucket_cursor, wt_g);

    // --- binned CSR build ---
    k_binA<<<(E_EDGES + 2047) / 2048, 1024, 0, stream>>>(src, dst, ew,
                                                         bucket_cursor, staged);
    k_binB2<<<NBKT, 1024, 0, stream>>>(bucket_cursor, staged,
                                       deg, offsets, csr8);

    // --- dense projections via MFMA (after staging is dead) ---
    k1_mfma<<<(N_NODES + 63) / 64, 256, 0, stream>>>(x, wt_g, b1,
                                                     xrelh, xroot);

    // --- layer 1 fused gather + node update + layer-2 projections ---
    k_layer1<<<N_NODES / 16, 256, 0, stream>>>(offsets, deg, csr8,
                                               xrelh, xroot, Wrel2, Wroot2, b2,
                                               h2rel, h2root);

    // --- layer 2 gather + log_softmax (fused) ---
    k_layer2<<<N_NODES / 32, 256, 0, stream>>>(offsets, deg, csr8,
                                               h2rel, h2root, out);
}

// Round 13
// 222.482 us; speedup vs baseline: 4.5332x; 1.0393x over previous
//
#include <hip/hip_runtime.h>
#include <math.h>

#define N_NODES 100000
#define E_EDGES 1600000
#define D_IN    128
#define H_MID   32
#define C_OUT   5

#define BSHIFT 9
#define BNODES 512    // nodes per bucket
#define NBKT   196    // ceil(100000/512); max bucket index 195
#define BCAP   9200   // per-bucket staging cap (mean 8163, +11 sigma)
#define SRC_BITS 17
#define SRC_MASK 0x1FFFF

#define KP 136        // LDS k-stride in bf16 units (x-tile)

typedef __attribute__((ext_vector_type(8))) short bf16x8;
typedef __attribute__((ext_vector_type(4))) float f32x4;

// round-to-nearest-even fp32 -> bf16 bits
__device__ inline unsigned f2bf(float f) {
    unsigned u = __float_as_uint(f);
    return (u + 0x7FFFu + ((u >> 16) & 1u)) >> 16;
}

// ---------------- prep: zero cursors + build transposed bf16 W1 panel ------
__global__ void k_prep(const float* __restrict__ Wrel,
                       const float* __restrict__ Wroot,
                       int* __restrict__ bucket_cursor,
                       unsigned short* __restrict__ wt_g) {
    int tid = threadIdx.x;                 // 256
    bucket_cursor[tid] = 0;                // 256 >= NBKT
    for (int i = tid; i < 64 * 128; i += 256) {
        int n = i >> 7, k = i & 127;
        float v = (n < H_MID) ? Wrel[k * H_MID + n] : Wroot[k * H_MID + (n - H_MID)];
        wt_g[i] = (unsigned short)f2bf(v);   // wt_g[n][k]
    }
}

// ---------------- K1 (MFMA): [xrel|xroot] = x @ [Wrel|Wroot] ----------------
__global__ __launch_bounds__(256) void k1_mfma(
    const float* __restrict__ x,
    const unsigned short* __restrict__ wt_g,
    const float* __restrict__ b1,
    unsigned short* __restrict__ xrelh,
    float* __restrict__ xroot) {
    __shared__ unsigned short xs[64 * KP];
    int tid = threadIdx.x;
    int nodeBase = blockIdx.x * 64;

    #pragma unroll
    for (int it = 0; it < 16; ++it) {
        int idx = it * 256 + tid;          // row*64 + kpair
        int row = idx >> 6, kp = idx & 63;
        int node = nodeBase + row;
        float2 v = make_float2(0.f, 0.f);
        if (node < N_NODES)
            v = *(const float2*)(x + (size_t)node * D_IN + kp * 2);
        unsigned pk = f2bf(v.x) | (f2bf(v.y) << 16);
        *(unsigned*)(xs + row * KP + kp * 2) = pk;
    }
    __syncthreads();

    int lane = tid & 63;
    int wv = tid >> 6;
    int m = lane & 15;
    int quad = lane >> 4;

    f32x4 acc[4];
    #pragma unroll
    for (int nt = 0; nt < 4; ++nt) acc[nt] = (f32x4){0.f, 0.f, 0.f, 0.f};

    #pragma unroll
    for (int kk = 0; kk < 4; ++kk) {
        int k0 = kk * 32 + quad * 8;
        bf16x8 a = *(const bf16x8*)(xs + (wv * 16 + m) * KP + k0);
        #pragma unroll
        for (int nt = 0; nt < 4; ++nt) {
            bf16x8 b = *(const bf16x8*)(wt_g + (nt * 16 + m) * 128 + k0);
            acc[nt] = __builtin_amdgcn_mfma_f32_16x16x32_bf16(a, b, acc[nt], 0, 0, 0);
        }
    }

    #pragma unroll
    for (int nt = 0; nt < 4; ++nt) {
        #pragma unroll
        for (int r = 0; r < 4; ++r) {
            int node = nodeBase + wv * 16 + quad * 4 + r;
            int colg = nt * 16 + m;
            if (node < N_NODES) {
                if (colg < H_MID) {
                    xrelh[(size_t)node * H_MID + colg] =
                        (unsigned short)f2bf(acc[nt][r]);
                } else {
                    int c = colg - H_MID;
                    xroot[(size_t)node * H_MID + c] = acc[nt][r] + b1[c];
                }
            }
        }
    }
}

// -------- Pass A: counting-sort 2048 edges by coarse bucket in LDS --------
// staged element: int2 { (dstLow9 << 17) | src17 , w_bits }  (8 B/edge)
__global__ __launch_bounds__(1024) void k_binA(
    const int* __restrict__ src,
    const int* __restrict__ dst,
    const float* __restrict__ ew,
    int* __restrict__ bucket_cursor,
    int2* __restrict__ staged) {
    __shared__ int cnt[NBKT];
    __shared__ int lstart[NBKT];
    __shared__ int gbase[NBKT];
    __shared__ int scanbuf[256];
    __shared__ int2 ebuf[2048];
    __shared__ short bbuf[2048];
    int tid = threadIdx.x;
    int eBase = blockIdx.x * 2048;

    if (tid < NBKT) cnt[tid] = 0;
    __syncthreads();

    int b[2], rank[2], packed[2], wbits[2];
    bool valid[2];
    #pragma unroll
    for (int u = 0; u < 2; ++u) {
        int e = eBase + u * 1024 + tid;
        valid[u] = (e < E_EDGES);
        b[u] = 0; rank[u] = 0; packed[u] = 0; wbits[u] = 0;
        if (valid[u]) {
            int d = dst[e];
            int s = src[e];
            wbits[u] = __float_as_int(ew[e]);
            b[u] = d >> BSHIFT;
            packed[u] = ((d & (BNODES - 1)) << SRC_BITS) | s;
            rank[u] = atomicAdd(&cnt[b[u]], 1);
        }
    }
    __syncthreads();

    if (tid < 256) scanbuf[tid] = (tid < NBKT) ? cnt[tid] : 0;
    __syncthreads();
    for (int off = 1; off < 256; off <<= 1) {
        int t = 0;
        if (tid < 256 && tid >= off) t = scanbuf[tid - off];
        __syncthreads();
        if (tid < 256) scanbuf[tid] += t;
        __syncthreads();
    }
    if (tid < NBKT) {
        lstart[tid] = scanbuf[tid] - cnt[tid];
        gbase[tid]  = atomicAdd(&bucket_cursor[tid], cnt[tid]);
    }
    __syncthreads();
    int total = scanbuf[NBKT - 1];

    #pragma unroll
    for (int u = 0; u < 2; ++u) {
        if (valid[u]) {
            int slot = lstart[b[u]] + rank[u];
            ebuf[slot] = make_int2(packed[u], wbits[u]);
            bbuf[slot] = (short)b[u];
        }
    }
    __syncthreads();

    for (int t = tid; t < total; t += 1024) {
        int2 ev = ebuf[t];
        int bb = bbuf[t];
        int gpos = gbase[bb] + (t - lstart[bb]);
        if (gpos < BCAP)
            staged[(size_t)bb * BCAP + gpos] = ev;
    }
}

// -------- Pass B: in-block base scan + per-bucket LDS hist + scatter -------
// 196 blocks of 1024 threads; 512-node buckets.
__global__ __launch_bounds__(1024) void k_binB2(
    const int* __restrict__ bucket_cursor,
    const int2* __restrict__ staged,
    int* __restrict__ deg,
    int* __restrict__ offsets,
    int2* __restrict__ csr8) {
    __shared__ int hist[BNODES];
    __shared__ int scanb[BNODES];
    __shared__ int cur[BNODES];
    __shared__ int sbase[256];
    int tid = threadIdx.x;
    int b = blockIdx.x;

    // in-block exclusive scan of clamped bucket counts -> base for bucket b
    if (tid < 256) {
        int c = (tid < NBKT) ? bucket_cursor[tid] : 0;
        sbase[tid] = (c > BCAP) ? BCAP : c;
    }
    if (tid < BNODES) hist[tid] = 0;
    __syncthreads();
    for (int off = 1; off < 256; off <<= 1) {
        int t = 0;
        if (tid < 256 && tid >= off) t = sbase[tid - off];
        __syncthreads();
        if (tid < 256) sbase[tid] += t;
        __syncthreads();
    }
    int count = bucket_cursor[b];
    if (count > BCAP) count = BCAP;
    int base = sbase[b] - count;           // exclusive
    int nodeBase = b << BSHIFT;
    const int2* sp = staged + (size_t)b * BCAP;

    for (int i = tid; i < count; i += 1024)
        atomicAdd(&hist[((unsigned)sp[i].x) >> SRC_BITS], 1);
    __syncthreads();

    // inclusive scan over 512 bins (first 512 threads)
    int v = 0;
    if (tid < BNODES) {
        v = hist[tid];
        scanb[tid] = v;
    }
    __syncthreads();
    for (int off = 1; off < BNODES; off <<= 1) {
        int t = 0;
        if (tid < BNODES && tid >= off) t = scanb[tid - off];
        __syncthreads();
        if (tid < BNODES) scanb[tid] += t;
        __syncthreads();
    }
    if (tid < BNODES) {
        int excl = scanb[tid] - v;
        int node = nodeBase + tid;
        if (node < N_NODES) {
            deg[node]     = v;
            offsets[node] = base + excl;
        }
        cur[tid] = excl;
    }
    __syncthreads();

    for (int i = tid; i < count; i += 1024) {
        int2 ev = sp[i];
        int local = ((unsigned)ev.x) >> SRC_BITS;
        int pos = atomicAdd(&cur[local], 1);
        csr8[base + pos] = make_int2(ev.x & SRC_MASK, ev.y);
    }
}

// -------- Layer 1 fused: bf16 gather-mean + root + relu + project ----------
// 32 nodes/block (512 threads), 16 lanes/node, 2 cols/lane, 8-deep MLP.
__global__ __launch_bounds__(512) void k_layer1(
    const int* __restrict__ offsets,
    const int* __restrict__ deg,
    const int2* __restrict__ csr8,
    const unsigned short* __restrict__ xrelh,
    const float* __restrict__ xroot,
    const float* __restrict__ Wrel2,
    const float* __restrict__ Wroot2,
    const float* __restrict__ b2,
    float* __restrict__ h2rel,
    float* __restrict__ h2root) {
    int node = blockIdx.x * 32 + (threadIdx.x >> 4);
    int lane = threadIdx.x & 15;           // 2 cols: 2*lane, 2*lane+1
    int beg = offsets[node];
    int dg  = deg[node];
    int end = beg + dg;

    float acc0 = 0.f, acc1 = 0.f;
    int i = beg;
    for (; i + 8 <= end; i += 8) {
        int2 e[8];
        unsigned v[8];
        #pragma unroll
        for (int u = 0; u < 8; ++u) e[u] = csr8[i + u];
        #pragma unroll
        for (int u = 0; u < 8; ++u)
            v[u] = *(const unsigned*)(xrelh + (size_t)e[u].x * H_MID + lane * 2);
        #pragma unroll
        for (int u = 0; u < 8; ++u) {
            float w = __int_as_float(e[u].y);
            acc0 += __uint_as_float((v[u] & 0xFFFFu) << 16) * w;
            acc1 += __uint_as_float(v[u] & 0xFFFF0000u) * w;
        }
    }
    for (; i < end; ++i) {
        int2 e0 = csr8[i];
        unsigned v0 = *(const unsigned*)(xrelh + (size_t)e0.x * H_MID + lane * 2);
        float w0 = __int_as_float(e0.y);
        acc0 += __uint_as_float((v0 & 0xFFFFu) << 16) * w0;
        acc1 += __uint_as_float(v0 & 0xFFFF0000u) * w0;
    }

    float inv = 1.0f / fmaxf((float)dg, 1.0f);
    float2 rt = *(const float2*)(xroot + (size_t)node * H_MID + lane * 2);
    float h0 = fmaxf(acc0 * inv + rt.x, 0.f);
    float h1 = fmaxf(acc1 * inv + rt.y, 0.f);

    float p[2 * C_OUT];
    #pragma unroll
    for (int j = 0; j < C_OUT; ++j) {
        p[j]         = h0 * Wrel2[(2 * lane) * C_OUT + j]
                     + h1 * Wrel2[(2 * lane + 1) * C_OUT + j];
        p[C_OUT + j] = h0 * Wroot2[(2 * lane) * C_OUT + j]
                     + h1 * Wroot2[(2 * lane + 1) * C_OUT + j];
    }
    #pragma unroll
    for (int mm = 8; mm > 0; mm >>= 1) {
        #pragma unroll
        for (int j = 0; j < 2 * C_OUT; ++j)
            p[j] += __shfl_xor(p[j], mm, 16);
    }
    if (lane == 0) {
        #pragma unroll
        for (int j = 0; j < C_OUT; ++j) {
            h2rel[(size_t)node * C_OUT + j]  = p[j];
            h2root[(size_t)node * C_OUT + j] = p[C_OUT + j] + b2[j];
        }
    }
}

// -------- Layer 2 + log_softmax fused: 32 nodes/block, 8 lanes/node --------
__global__ __launch_bounds__(256) void k_layer2(
    const int* __restrict__ offsets,
    const int* __restrict__ deg,
    const int2* __restrict__ csr8,
    const float* __restrict__ h2rel,
    const float* __restrict__ h2root,
    float* __restrict__ out) {
    int node = blockIdx.x * 32 + (threadIdx.x >> 3);
    int lane = threadIdx.x & 7;
    int beg = offsets[node];
    int dg  = deg[node];
    int end = beg + dg;

    float acc = 0.f;
    if (lane < C_OUT) {
        int i = beg;
        for (; i + 8 <= end; i += 8) {
            int s[8];
            float v[8];
            #pragma unroll
            for (int u = 0; u < 8; ++u) s[u] = csr8[i + u].x;
            #pragma unroll
            for (int u = 0; u < 8; ++u)
                v[u] = h2rel[(size_t)s[u] * C_OUT + lane];
            #pragma unroll
            for (int u = 0; u < 8; ++u) acc += v[u];
        }
        for (; i < end; ++i)
            acc += h2rel[(size_t)csr8[i].x * C_OUT + lane];
    }
    float inv = 1.0f / fmaxf((float)dg, 1.0f);
    float o = (lane < C_OUT)
                  ? acc * inv + h2root[(size_t)node * C_OUT + lane]
                  : -INFINITY;
    float m = o;
    #pragma unroll
    for (int dd = 4; dd > 0; dd >>= 1) m = fmaxf(m, __shfl_xor(m, dd, 8));
    float e = (lane < C_OUT) ? expf(o - m) : 0.f;
    float ssum = e;
    #pragma unroll
    for (int dd = 4; dd > 0; dd >>= 1) ssum += __shfl_xor(ssum, dd, 8);
    float lse = m + logf(ssum);
    if (lane < C_OUT)
        out[(size_t)node * C_OUT + lane] = o - lse;
}

extern "C" void kernel_launch(void* const* d_in, const int* in_sizes, int n_in,
                              void* d_out, int out_size, void* d_ws, size_t ws_size,
                              hipStream_t stream) {
    const float* x      = (const float*)d_in[0];
    const int*   ei     = (const int*)d_in[1];
    const float* ew     = (const float*)d_in[2];
    const float* Wrel1  = (const float*)d_in[3];
    const float* Wroot1 = (const float*)d_in[4];
    const float* b1     = (const float*)d_in[5];
    const float* Wrel2  = (const float*)d_in[6];
    const float* Wroot2 = (const float*)d_in[7];
    const float* b2     = (const float*)d_in[8];
    float* out = (float*)d_out;

    const int* src = ei;
    const int* dst = ei + E_EDGES;

    // Workspace (4B units). staged (196*9200 int2 = 14.4MB) aliases
    // xrelh+xroot (6.4+12.8=19.2MB) — dead before k1_mfma writes there.
    char* ws = (char*)d_ws;
    int*   deg           = (int*)ws;                            // N
    int*   bucket_cursor = deg + N_NODES;                       // 256
    unsigned short* wt_g = (unsigned short*)(bucket_cursor + 256); // 64*128 bf16
    int*   offsets       = (int*)(wt_g + 64 * 128);             // N
    int2*  csr8          = (int2*)(offsets + N_NODES);          // E int2
    unsigned short* xrelh = (unsigned short*)(csr8 + E_EDGES);  // 32N ushort
    float* xroot         = (float*)(xrelh + (size_t)N_NODES * H_MID); // 32N
    float* h2rel         = xroot + (size_t)N_NODES * H_MID;     // 5N
    float* h2root        = h2rel + (size_t)N_NODES * C_OUT;     // 5N
    int2*  staged        = (int2*)xrelh;                        // alias

    // --- prep: zero cursors + bf16 W panel ---
    k_prep<<<1, 256, 0, stream>>>(Wrel1, Wroot1, bucket_cursor, wt_g);

    // --- binned CSR build ---
    k_binA<<<(E_EDGES + 2047) / 2048, 1024, 0, stream>>>(src, dst, ew,
                                                         bucket_cursor, staged);
    k_binB2<<<NBKT, 1024, 0, stream>>>(bucket_cursor, staged,
                                       deg, offsets, csr8);

    // --- dense projections via MFMA (after staging is dead) ---
    k1_mfma<<<(N_NODES + 63) / 64, 256, 0, stream>>>(x, wt_g, b1,
                                                     xrelh, xroot);

    // --- layer 1 fused gather + node update + layer-2 projections ---
    k_layer1<<<N_NODES / 32, 512, 0, stream>>>(offsets, deg, csr8,
                                               xrelh, xroot, Wrel2, Wroot2, b2,
                                               h2rel, h2root);

    // --- layer 2 gather + log_softmax (fused) ---
    k_layer2<<<N_NODES / 32, 256, 0, stream>>>(offsets, deg, csr8,
                                               h2rel, h2root, out);
}